// Round 16
// baseline (462.773 us; speedup 1.0000x reference)
//
#include <hip/hip_runtime.h>
#include <math.h>

// Problem constants (from reference)
constexpr int NN   = 50000;   // nodes
constexpr int EE   = 300000;  // edges
constexpr int IND  = 1024;    // IN_DIM
constexpr int CODE = 768;     // CODE_DIM
constexpr int HID  = 256;

constexpr int NRT  = (NN + 127) / 128;    // 391 row tiles

constexpr int CS_BLKS  = 1024;                 // colstats blocks
constexpr int DEG_BLKS = (EE + 255) / 256;     // 1172
constexpr int PW_BLKS  = 1536;                 // weight-cvt blocks

typedef __bf16 bf16_t;
typedef bf16_t bf16x4 __attribute__((ext_vector_type(4)));
typedef bf16_t bf16x8 __attribute__((ext_vector_type(8)));
typedef float  f32x4  __attribute__((ext_vector_type(4)));

__device__ __forceinline__ f32x4 mfma16(bf16x8 a, bf16x8 b, f32x4 c) {
    return __builtin_amdgcn_mfma_f32_16x16x32_bf16(a, b, c, 0, 0, 0);
}

// async global->LDS, 16B per lane, wave-uniform LDS base + lane*16
#define GLOAD_LDS16(gp, lp) __builtin_amdgcn_global_load_lds(                         \
    (__attribute__((address_space(1))) void*)(gp),                                    \
    (__attribute__((address_space(3))) void*)(lp), 16, 0, 0)

// load 4 consecutive bf16 -> f32x4
__device__ __forceinline__ f32x4 ld_bf4(const bf16_t* p) {
    bf16x4 v = *(const bf16x4*)p;
    f32x4 r;
    r[0] = (float)v[0]; r[1] = (float)v[1]; r[2] = (float)v[2]; r[3] = (float)v[3];
    return r;
}

// ---------------------------------------------------------------------------
// Fused prep: colstats (blocks 0..1023) + degree count (next 1172) +
// weight bf16 conversion (next 1536). All independent, disjoint outputs.
__global__ void prep1_kernel(const float* __restrict__ x, float* __restrict__ sums,
                             const int* __restrict__ ei, int* __restrict__ deg,
                             const float* __restrict__ W_in, const float* __restrict__ W1,
                             const float* __restrict__ W2, bf16_t* __restrict__ Wmh,
                             bf16_t* __restrict__ Wh1, bf16_t* __restrict__ Wh2)
{
    int b = blockIdx.x, t = threadIdx.x;
    if (b < CS_BLKS) {
        // per-column sum/sumsq of x[:, 768:1024]
        float s = 0.f, s2 = 0.f;
        for (int row = b; row < NN; row += CS_BLKS) {
            float v = x[(size_t)row * IND + CODE + t];
            s += v; s2 += v * v;
        }
        atomicAdd(&sums[t], s);
        atomicAdd(&sums[256 + t], s2);
    } else if (b < CS_BLKS + DEG_BLKS) {
        int e = (b - CS_BLKS) * 256 + t;
        if (e < EE) atomicAdd(&deg[ei[EE + e]], 1);
    } else {
        int bb = b - CS_BLKS - DEG_BLKS;
        if (bb < 1024) {
            size_t i = (size_t)bb * 256 + t;
            Wmh[i] = (bf16_t)W_in[i];
        } else if (bb < 1280) {
            size_t i = (size_t)(bb - 1024) * 256 + t;
            Wh1[i] = (bf16_t)W1[i];
        } else {
            size_t i = (size_t)(bb - 1280) * 256 + t;
            Wh2[i] = (bf16_t)W2[i];
        }
    }
}

constexpr int SCB = 1024;                       // elems per scan chunk
constexpr int SCN = (NN + SCB - 1) / SCB;       // 49

// xin build (normalized bf16, reference layout) + chunk-sum scan in last block.
// xin[row][0:256]    = (x[row][768+j] - mean_j) * invstd_j
// xin[row][256:1024] = x[row][0:768] / max(||x_code||, 1e-12)
__global__ void xin_scan_kernel(const float* __restrict__ x, const float* __restrict__ sums,
                                bf16_t* __restrict__ xin, const int* __restrict__ deg,
                                int* __restrict__ bsum)
{
    if (blockIdx.x == gridDim.x - 1) {
        // fused scan pass1+2 over deg chunks (256 threads: 4 waves)
        __shared__ int sh[SCN];
        int tid = threadIdx.x, w = tid >> 6, lane = tid & 63;
        for (int b = w; b < SCN; b += 4) {
            int s = 0;
            for (int i = lane; i < SCB; i += 64) {
                int idx = b * SCB + i;
                if (idx < NN) s += deg[idx];
            }
            #pragma unroll
            for (int off = 32; off; off >>= 1) s += __shfl_xor(s, off);
            if (lane == 0) sh[b] = s;
        }
        __syncthreads();
        if (tid == 0) {
            int run = 0;
            for (int b = 0; b < SCN; b++) { int v = sh[b]; bsum[b] = run; run += v; }
        }
        return;
    }
    int lane = threadIdx.x & 63, wid = threadIdx.x >> 6;
    int row  = blockIdx.x * 4 + wid;
    if (row >= NN) return;
    const f32x4* x4 = (const f32x4*)(x + (size_t)row * IND);
    f32x4 v[4];
    #pragma unroll
    for (int i = 0; i < 4; i++) v[i] = x4[lane + 64 * i];
    float s = 0.f;
    #pragma unroll
    for (int i = 0; i < 3; i++)
        s += v[i][0] * v[i][0] + v[i][1] * v[i][1] + v[i][2] * v[i][2] + v[i][3] * v[i][3];
    #pragma unroll
    for (int off = 32; off; off >>= 1) s += __shfl_xor(s, off);
    float inr = 1.f / fmaxf(sqrtf(s), 1e-12f);

    bf16_t* xr = xin + (size_t)row * IND;
    #pragma unroll
    for (int i = 0; i < 3; i++) {
        bf16x4 o;
        #pragma unroll
        for (int q = 0; q < 4; q++) o[q] = (bf16_t)(v[i][q] * inr);
        *(bf16x4*)(xr + 256 + 4 * (lane + 64 * i)) = o;
    }
    {
        bf16x4 o;
        #pragma unroll
        for (int q = 0; q < 4; q++) {
            int j = 4 * lane + q;
            float mean = sums[j] / (float)NN;
            float var  = (sums[256 + j] - (float)NN * mean * mean) / (float)(NN - 1);
            float invstd = 1.f / fmaxf(sqrtf(fmaxf(var, 0.f)), 1e-6f);
            o[q] = (bf16_t)((v[3][q] - mean) * invstd);
        }
        *(bf16x4*)(xr + 4 * lane) = o;
    }
}

// ---------------------------------------------------------------------------
// Pure-bf16 MFMA GEMM, global_load_lds staging, double-buffered, 32.5 KB LDS.
// MODE 1 (K=1024): epilogue relu(acc + bin[col]) -> bf16 table only.
// MODE 0 (K=256, FATTN): epilogue attention logits + bf16 xh gather table.
// Tile 128x128, BK=32, 256 threads = 4 waves (2x2), 64x64 per wave.

// stage 128x32 bf16 tile; LDS slot p of row holds global chunk p^((row>>1)&3)
__device__ __forceinline__ void stage_b(const bf16_t* __restrict__ src, int n0, int ldk,
                                        int maxrow, int k0, bf16_t* buf, int tid) {
    int w = tid >> 6, l = tid & 63;
    #pragma unroll
    for (int i = 0; i < 2; i++) {
        int gbase = w * 128 + i * 64;
        bf16_t* dst = buf + gbase * 8;     // wave-uniform base (granule*8 bf16)
        int g = gbase + l;
        int col = g >> 2, p = g & 3;
        int gs = p ^ ((col >> 1) & 3);
        int row = n0 + col;
        if (row > maxrow) row = maxrow;
        const bf16_t* gp = src + (size_t)row * ldk + k0 + gs * 8;
        GLOAD_LDS16(gp, dst);
    }
}

template<int MODE, int K, int FATTN>
__global__ __launch_bounds__(256) void gemm_mfma_kernel(
    const bf16_t* __restrict__ A16, const bf16_t* __restrict__ Bh,
    const float* __restrict__ bin, const float* __restrict__ a_src,
    const float* __restrict__ a_dst, bf16_t* __restrict__ xhb,
    float* __restrict__ al_s, float* __restrict__ al_d)
{
    __shared__ bf16_t Asb[2][128 * 32];    // 16 KB
    __shared__ bf16_t Bhs[2][128 * 32];    // 16 KB
    constexpr int NT = K / 32;

    int tid  = threadIdx.x;
    int lane = tid & 63;
    int w    = tid >> 6;
    int wr   = w >> 1, wc = w & 1;
    int r0   = blockIdx.x * 128, n0 = blockIdx.y * 128;

    f32x4 acc[4][4];
    #pragma unroll
    for (int i = 0; i < 4; i++)
        #pragma unroll
        for (int j = 0; j < 4; j++) acc[i][j] = (f32x4)0.f;

    int kc = lane >> 4, fr = lane & 15;    // kc doubles as fq in epilogue

    stage_b(A16, r0, K, NN - 1, 0, Asb[0], tid);
    stage_b(Bh, n0, K, 255, 0, Bhs[0], tid);
    __syncthreads();   // vmcnt(0) drain: tile 0 resident

    for (int t = 0; t < NT; ++t) {
        int buf = t & 1;
        if (t + 1 < NT) {   // issue next tile; lands during this compute phase
            stage_b(A16, r0, K, NN - 1, (t + 1) * 32, Asb[buf ^ 1], tid);
            stage_b(Bh, n0, K, 255, (t + 1) * 32, Bhs[buf ^ 1], tid);
        }
        // ---- fragments + MFMA ----
        const bf16_t* Ab = Asb[buf];
        const bf16_t* Hb = Bhs[buf];
        bf16x8 ahi[4];
        #pragma unroll
        for (int mf = 0; mf < 4; mf++) {
            int r  = wr * 64 + mf * 16 + fr;
            int pr = kc ^ ((r >> 1) & 3);
            ahi[mf] = *(const bf16x8*)&Ab[r * 32 + pr * 8];
        }
        #pragma unroll
        for (int nf = 0; nf < 4; nf++) {
            int c  = wc * 64 + nf * 16 + fr;
            int pr = kc ^ ((c >> 1) & 3);
            bf16x8 bhi = *(const bf16x8*)&Hb[c * 32 + pr * 8];
            #pragma unroll
            for (int mf = 0; mf < 4; mf++)
                acc[mf][nf] = mfma16(ahi[mf], bhi, acc[mf][nf]);
        }
        __syncthreads();  // tile t+1 landed; all reads of buf done
    }

    // ---- epilogue ----
    int head = blockIdx.y * 2 + wc;
    float asv[4], adv[4];
    if (FATTN) {
        #pragma unroll
        for (int nf = 0; nf < 4; nf++) {
            asv[nf] = a_src[head * 64 + nf * 16 + fr];
            adv[nf] = a_dst[head * 64 + nf * 16 + fr];
        }
    }
    #pragma unroll
    for (int mf = 0; mf < 4; mf++) {
        #pragma unroll
        for (int j = 0; j < 4; j++) {
            int row = r0 + wr * 64 + mf * 16 + kc * 4 + j;
            bool ok = row < NN;
            float s = 0.f, d = 0.f;
            #pragma unroll
            for (int nf = 0; nf < 4; nf++) {
                int col = n0 + wc * 64 + nf * 16 + fr;
                float v = acc[mf][nf][j];
                if (MODE == 1) v = fmaxf(v + bin[col], 0.f);
                if (FATTN) { s += v * asv[nf]; d += v * adv[nf]; }
                if (ok) xhb[(size_t)row * HID + col] = (bf16_t)v;   // bf16 table
            }
            if (FATTN) {
                #pragma unroll
                for (int off = 1; off < 16; off <<= 1) {
                    s += __shfl_xor(s, off);
                    d += __shfl_xor(d, off);
                }
                if (ok && fr == 0) {
                    al_s[row * 4 + head] = s;
                    al_d[row * 4 + head] = d;
                }
            }
        }
    }
}

// ---------------------------------------------------------------------------
__global__ void scan_pass3(const int* __restrict__ deg, const int* __restrict__ boffs,
                           int* __restrict__ row_ptr, int* __restrict__ cursor) {
    int b = blockIdx.x, t = threadIdx.x;
    int base = b * SCB + t * 4;
    int d[4]; int tot = 0;
    #pragma unroll
    for (int i = 0; i < 4; i++) { int idx = base + i; d[i] = (idx < NN) ? deg[idx] : 0; tot += d[i]; }
    int v = tot;
    for (int off = 1; off < 64; off <<= 1) {
        int u = __shfl_up(v, off);
        if ((t & 63) >= off) v += u;
    }
    __shared__ int wsum[4];
    if ((t & 63) == 63) wsum[t >> 6] = v;
    __syncthreads();
    int woff = 0;
    for (int j = 0; j < (t >> 6); j++) woff += wsum[j];
    int run = boffs[b] + woff + v - tot;
    #pragma unroll
    for (int i = 0; i < 4; i++) {
        int idx = base + i;
        if (idx < NN) {
            cursor[idx] = run;
            run += d[i];
            row_ptr[idx + 1] = run;
        }
    }
    if (b == 0 && t == 0) row_ptr[0] = 0;
}

// fill CSR with materialized src / type / weight (no eid indirection later)
__global__ void fill_kernel(const int* __restrict__ ei, const int* __restrict__ etype,
                            const float* __restrict__ ew, int* __restrict__ cursor,
                            int* __restrict__ csr_src, int* __restrict__ csr_t,
                            float* __restrict__ csr_w) {
    int e = blockIdx.x * 256 + threadIdx.x;
    if (e >= EE) return;
    int dst = ei[EE + e];
    int pos = atomicAdd(&cursor[dst], 1);
    csr_src[pos] = ei[e];
    csr_t[pos]   = etype[e];
    csr_w[pos]   = ew[e];
}

// ---------------------------------------------------------------------------
// h_new[d] = h[d] + sum_{e: dst=d} (h[src_e] + rel_emb[type_e]*w_e)
// All h reads from the bf16 table (self + gathers); accumulate fp32.
// Masked 8-deep chunks. Writes bf16 only.
__global__ void relagg_kernel(const bf16_t* __restrict__ h16, const int* __restrict__ row_ptr,
                              const int* __restrict__ csr_src, const int* __restrict__ csr_t,
                              const float* __restrict__ csr_w,
                              const float* __restrict__ rel_emb,
                              bf16_t* __restrict__ out16)
{
    int lane = threadIdx.x & 63, wid = threadIdx.x >> 6;
    int node = blockIdx.x * 4 + wid;
    if (node >= NN) return;
    int c0 = lane * 4;
    f32x4 acc = ld_bf4(h16 + (size_t)node * HID + c0);
    float wsum[5] = {0.f, 0.f, 0.f, 0.f, 0.f};
    int beg = row_ptr[node], end = row_ptr[node + 1];
    for (int k = beg; k < end; k += 8) {
        int s[8], tt[8]; float ww[8], vm[8];
        #pragma unroll
        for (int j = 0; j < 8; j++) {
            int kk = k + j;
            bool valid = kk < end;
            kk = valid ? kk : (end - 1);
            s[j]  = csr_src[kk];
            tt[j] = csr_t[kk];
            ww[j] = valid ? csr_w[kk] : 0.f;
            vm[j] = valid ? 1.f : 0.f;
        }
        f32x4 xv[8];
        #pragma unroll
        for (int j = 0; j < 8; j++) xv[j] = ld_bf4(h16 + (size_t)s[j] * HID + c0);
        #pragma unroll
        for (int j = 0; j < 8; j++) {
            acc += vm[j] * xv[j];
            #pragma unroll
            for (int r = 0; r < 5; r++) wsum[r] += (tt[j] == r) ? ww[j] : 0.f;
        }
    }
    #pragma unroll
    for (int r = 0; r < 5; r++)
        acc += wsum[r] * *(const f32x4*)(rel_emb + r * HID + c0);
    bf16x4 a16;
    #pragma unroll
    for (int i = 0; i < 4; i++) a16[i] = (bf16_t)acc[i];
    *(bf16x4*)(out16 + (size_t)node * HID + c0) = a16;
}

// GAT aggregation over bf16 xh gather table. Lane owns 4 consecutive cols
// (head lane>>4). Masked 8-deep chunks (e=-inf for invalid => exact no-op).
// Residual read from bf16 table (own node only). FINAL=0 overwrites res16
// in place (per-element read-before-write, same thread -> safe); FINAL=1
// fuses the output projection.
template<int FINAL>
__global__ void gat_kernel(const bf16_t* __restrict__ xhb, const float* __restrict__ al_s,
                           const float* __restrict__ al_d, const int* __restrict__ row_ptr,
                           const int* __restrict__ csr_src, const bf16_t* __restrict__ res16,
                           const float* __restrict__ bias, const float* __restrict__ ln_g,
                           const float* __restrict__ ln_b, bf16_t* __restrict__ out16,
                           const float* __restrict__ W_out, const float* __restrict__ b_out,
                           float* __restrict__ final_out)
{
    int lane = threadIdx.x & 63, wid = threadIdx.x >> 6;
    int node = blockIdx.x * 4 + wid;
    if (node >= NN) return;
    int hh = lane >> 4;                 // this lane's head
    int c0 = lane * 4;                  // 4 consecutive cols, all head hh

    float ald = al_d[node * 4 + hh];
    float m, den;
    f32x4 acc;

    // self-loop first (initializes the online state)
    {
        float als = al_s[node * 4 + hh];
        float e = als + ald;
        e = (e >= 0.f) ? e : 0.2f * e;
        m = e; den = 1.f;
        acc = ld_bf4(xhb + (size_t)node * HID + c0);
    }

    int beg = row_ptr[node], end = row_ptr[node + 1];
    for (int k = beg; k < end; k += 8) {
        int s[8]; float als[8];
        #pragma unroll
        for (int j = 0; j < 8; j++) {
            int kk = k + j;
            bool valid = kk < end;
            s[j] = csr_src[valid ? kk : (end - 1)];
            als[j] = valid ? 0.f : -INFINITY;   // -inf marks masked
        }
        #pragma unroll
        for (int j = 0; j < 8; j++)
            if (als[j] == 0.f) als[j] = al_s[s[j] * 4 + hh];
        f32x4 xv[8];
        #pragma unroll
        for (int j = 0; j < 8; j++) xv[j] = ld_bf4(xhb + (size_t)s[j] * HID + c0);
        #pragma unroll
        for (int j = 0; j < 8; j++) {
            float e = als[j] + ald;               // -inf stays -inf
            e = (e >= 0.f) ? e : 0.2f * e;
            float mn  = fmaxf(m, e);              // masked: mn == m
            float f   = __expf(m - mn);           // masked: 1 (exact)
            float wgt = __expf(e - mn);           // masked: 0 (exact)
            m   = mn;
            den = den * f + wgt;
            acc = acc * f + wgt * xv[j];
        }
    }

    f32x4 bia = *(const f32x4*)(bias + c0);
    f32x4 res = ld_bf4(res16 + (size_t)node * HID + c0);
    f32x4 z;
    float rd = 1.f / (den + 1e-16f);
    #pragma unroll
    for (int i = 0; i < 4; i++) z[i] = acc[i] * rd + bia[i] + res[i];

    float s = z[0] + z[1] + z[2] + z[3];
    #pragma unroll
    for (int off = 32; off; off >>= 1) s += __shfl_xor(s, off);
    float mean = s * (1.f / 256.f);
    float vp = 0.f;
    #pragma unroll
    for (int i = 0; i < 4; i++) { float d2 = z[i] - mean; vp += d2 * d2; }
    #pragma unroll
    for (int off = 32; off; off >>= 1) vp += __shfl_xor(vp, off);
    float rstd = rsqrtf(vp * (1.f / 256.f) + 1e-5f);

    f32x4 g = *(const f32x4*)(ln_g + c0);
    f32x4 bb = *(const f32x4*)(ln_b + c0);
    if (FINAL) {
        f32x4 wo = *(const f32x4*)(W_out + c0);
        float dot = 0.f;
        #pragma unroll
        for (int i = 0; i < 4; i++)
            dot += ((z[i] - mean) * rstd * g[i] + bb[i]) * wo[i];
        #pragma unroll
        for (int off = 32; off; off >>= 1) dot += __shfl_xor(dot, off);
        if (lane == 0) final_out[node] = dot + b_out[0];
    } else {
        bf16x4 o16;
        #pragma unroll
        for (int i = 0; i < 4; i++)
            o16[i] = (bf16_t)((z[i] - mean) * rstd * g[i] + bb[i]);
        *(bf16x4*)(out16 + (size_t)node * HID + c0) = o16;
    }
}

// ---------------------------------------------------------------------------
extern "C" void kernel_launch(void* const* d_in, const int* in_sizes, int n_in,
                              void* d_out, int out_size, void* d_ws, size_t ws_size,
                              hipStream_t stream) {
    const float* x       = (const float*)d_in[0];
    const int*   ei      = (const int*)d_in[1];
    const int*   etype   = (const int*)d_in[2];
    const float* ew      = (const float*)d_in[3];
    const float* rel_emb = (const float*)d_in[4];
    const float* W_in    = (const float*)d_in[5];
    const float* b_in    = (const float*)d_in[6];
    const float* W1      = (const float*)d_in[7];
    const float* a1s     = (const float*)d_in[8];
    const float* a1d     = (const float*)d_in[9];
    const float* b1      = (const float*)d_in[10];
    const float* W2      = (const float*)d_in[11];
    const float* a2s     = (const float*)d_in[12];
    const float* a2d     = (const float*)d_in[13];
    const float* b2      = (const float*)d_in[14];
    const float* ln1g    = (const float*)d_in[15];
    const float* ln1b    = (const float*)d_in[16];
    const float* ln2g    = (const float*)d_in[17];
    const float* ln2b    = (const float*)d_in[18];
    const float* W_out   = (const float*)d_in[19];
    const float* b_out   = (const float*)d_in[20];
    float* out = (float*)d_out;

    char* ws = (char*)d_ws;
    auto alloc = [&](size_t bytes) {
        void* p = (void*)ws;
        ws += (bytes + 255) & ~(size_t)255;
        return p;
    };
    // stats_s and deg contiguous -> single memset covers both
    float*  stats_s  = (float*)alloc(512 * 4);                 // 2048 B (256-aligned)
    int*    deg      = (int*)alloc((size_t)NN * 4);
    bf16_t* xin16    = (bf16_t*)alloc((size_t)NN * IND * 2);   // normalized input, bf16
    bf16_t* xhb      = (bf16_t*)alloc((size_t)NN * HID * 2);   // xh gather table
    bf16_t* gin16    = (bf16_t*)alloc((size_t)NN * HID * 2);   // h / residual table
    bf16_t* hb16     = (bf16_t*)alloc((size_t)NN * HID * 2);   // bf16 h0
    bf16_t* wmh      = (bf16_t*)alloc((size_t)HID * IND * 2);
    bf16_t* w1h      = (bf16_t*)alloc((size_t)HID * HID * 2);
    bf16_t* w2h      = (bf16_t*)alloc((size_t)HID * HID * 2);
    float*  al_s     = (float*)alloc((size_t)NN * 4 * 4);
    float*  al_d     = (float*)alloc((size_t)NN * 4 * 4);
    int*    row_ptr  = (int*)alloc((size_t)(NN + 1) * 4);
    int*    cursor   = (int*)alloc((size_t)NN * 4);
    int*    csr_src  = (int*)alloc((size_t)EE * 4);
    int*    csr_t    = (int*)alloc((size_t)EE * 4);
    float*  csr_w    = (float*)alloc((size_t)EE * 4);
    int*    bsum     = (int*)alloc(64 * 4);

    // one memset: stats_s (2 KB) + deg (200 KB), contiguous
    hipMemsetAsync(stats_s, 0, 512 * 4 + (size_t)NN * 4, stream);

    // fused prep: colstats + degree count + weight cvt
    prep1_kernel<<<CS_BLKS + DEG_BLKS + PW_BLKS, 256, 0, stream>>>(
        x, stats_s, ei, deg, W_in, W1, W2, wmh, w1h, w2h);

    // xin build + deg chunk-scan (last block)
    int xinBlocks = (NN + 3) / 4;
    xin_scan_kernel<<<xinBlocks + 1, 256, 0, stream>>>(x, stats_s, xin16, deg, bsum);

    // CSR finalize
    scan_pass3<<<SCN, 256, 0, stream>>>(deg, bsum, row_ptr, cursor);
    fill_kernel<<<DEG_BLKS, 256, 0, stream>>>(ei, etype, ew, cursor,
                                              csr_src, csr_t, csr_w);

    dim3 g1(NRT, 2);

    // h0 = relu(xin @ W_in^T + b_in)  -> hb16 (bf16)
    gemm_mfma_kernel<1, 1024, 0><<<g1, 256, 0, stream>>>(
        xin16, wmh, b_in, nullptr, nullptr, hb16, nullptr, nullptr);

    int nodeBlocks = (NN + 3) / 4;

    // relational aggregation (bf16 reads) -> gin16 (bf16 h / residual table)
    relagg_kernel<<<nodeBlocks, 256, 0, stream>>>(hb16, row_ptr, csr_src, csr_t,
                                                  csr_w, rel_emb, gin16);

    // ---- GAT layer 1 (bf16 xh GEMM -> xhb + fused attention logits) ----
    gemm_mfma_kernel<0, 256, 1><<<g1, 256, 0, stream>>>(
        gin16, w1h, nullptr, a1s, a1d, xhb, al_s, al_d);
    // gat<0>: residual from gin16, overwrites gin16 in place (h1 table)
    gat_kernel<0><<<nodeBlocks, 256, 0, stream>>>(xhb, al_s, al_d, row_ptr, csr_src,
                                                  gin16, b1, ln1g, ln1b, gin16,
                                                  nullptr, nullptr, nullptr);

    // ---- GAT layer 2 (final projection fused) ----
    gemm_mfma_kernel<0, 256, 1><<<g1, 256, 0, stream>>>(
        gin16, w2h, nullptr, a2s, a2d, xhb, al_s, al_d);
    gat_kernel<1><<<nodeBlocks, 256, 0, stream>>>(xhb, al_s, al_d, row_ptr, csr_src,
                                                  gin16, b2, ln2g, ln2b, nullptr,
                                                  W_out, b_out, out);
}

// Round 17
// 405.449 us; speedup vs baseline: 1.1414x; 1.1414x over previous
//
#include <hip/hip_runtime.h>
#include <math.h>

// Problem constants (from reference)
constexpr int NN   = 50000;   // nodes
constexpr int EE   = 300000;  // edges
constexpr int IND  = 1024;    // IN_DIM
constexpr int CODE = 768;     // CODE_DIM
constexpr int HID  = 256;

constexpr int NRT  = (NN + 127) / 128;    // 391 row tiles

typedef __bf16 bf16_t;
typedef bf16_t bf16x4 __attribute__((ext_vector_type(4)));
typedef bf16_t bf16x8 __attribute__((ext_vector_type(8)));
typedef float  f32x4  __attribute__((ext_vector_type(4)));

__device__ __forceinline__ f32x4 mfma16(bf16x8 a, bf16x8 b, f32x4 c) {
    return __builtin_amdgcn_mfma_f32_16x16x32_bf16(a, b, c, 0, 0, 0);
}

// async global->LDS, 16B per lane, wave-uniform LDS base + lane*16
#define GLOAD_LDS16(gp, lp) __builtin_amdgcn_global_load_lds(                         \
    (__attribute__((address_space(1))) void*)(gp),                                    \
    (__attribute__((address_space(3))) void*)(lp), 16, 0, 0)

// load 4 consecutive bf16 -> f32x4
__device__ __forceinline__ f32x4 ld_bf4(const bf16_t* p) {
    bf16x4 v = *(const bf16x4*)p;
    f32x4 r;
    r[0] = (float)v[0]; r[1] = (float)v[1]; r[2] = (float)v[2]; r[3] = (float)v[3];
    return r;
}

// ---------------------------------------------------------------------------
// Stage 1: per-column sum/sumsq of x[:, 768:1024]
__global__ void colstats_kernel(const float* __restrict__ x, float* __restrict__ sums) {
    int col = threadIdx.x;             // 0..255
    float s = 0.f, s2 = 0.f;
    for (int row = blockIdx.x; row < NN; row += gridDim.x) {
        float v = x[(size_t)row * IND + CODE + col];
        s += v; s2 += v * v;
    }
    atomicAdd(&sums[col], s);
    atomicAdd(&sums[256 + col], s2);
}

// Stage 2: build xin as normalized bf16 in reference layout:
// xin[row][0:256]    = (x[row][768+j] - mean_j) * invstd_j
// xin[row][256:1024] = x[row][0:768] / max(||x_code||, 1e-12)
__global__ void xin_kernel(const float* __restrict__ x, const float* __restrict__ sums,
                           bf16_t* __restrict__ xin)
{
    int lane = threadIdx.x & 63, wid = threadIdx.x >> 6;
    int row  = blockIdx.x * 4 + wid;
    if (row >= NN) return;
    const f32x4* x4 = (const f32x4*)(x + (size_t)row * IND);
    f32x4 v[4];
    #pragma unroll
    for (int i = 0; i < 4; i++) v[i] = x4[lane + 64 * i];
    float s = 0.f;
    #pragma unroll
    for (int i = 0; i < 3; i++)
        s += v[i][0] * v[i][0] + v[i][1] * v[i][1] + v[i][2] * v[i][2] + v[i][3] * v[i][3];
    #pragma unroll
    for (int off = 32; off; off >>= 1) s += __shfl_xor(s, off);
    float inr = 1.f / fmaxf(sqrtf(s), 1e-12f);

    bf16_t* xr = xin + (size_t)row * IND;
    #pragma unroll
    for (int i = 0; i < 3; i++) {
        bf16x4 o;
        #pragma unroll
        for (int q = 0; q < 4; q++) o[q] = (bf16_t)(v[i][q] * inr);
        *(bf16x4*)(xr + 256 + 4 * (lane + 64 * i)) = o;
    }
    {
        bf16x4 o;
        #pragma unroll
        for (int q = 0; q < 4; q++) {
            int j = 4 * lane + q;
            float mean = sums[j] / (float)NN;
            float var  = (sums[256 + j] - (float)NN * mean * mean) / (float)(NN - 1);
            float invstd = 1.f / fmaxf(sqrtf(fmaxf(var, 0.f)), 1e-6f);
            o[q] = (bf16_t)((v[3][q] - mean) * invstd);
        }
        *(bf16x4*)(xr + 4 * lane) = o;
    }
}

// all weights -> bf16 in one launch: W_in (256x1024), W1, W2 (256x256 each)
__global__ void prep_all_kernel(const float* __restrict__ W_in, const float* __restrict__ W1,
                                const float* __restrict__ W2, bf16_t* __restrict__ Wmh,
                                bf16_t* __restrict__ Wh1, bf16_t* __restrict__ Wh2)
{
    int b = blockIdx.x, t = threadIdx.x;
    if (b < 1024) {
        size_t i = (size_t)b * 256 + t;
        Wmh[i] = (bf16_t)W_in[i];
    } else if (b < 1280) {
        size_t i = (size_t)(b - 1024) * 256 + t;
        Wh1[i] = (bf16_t)W1[i];
    } else {
        size_t i = (size_t)(b - 1280) * 256 + t;
        Wh2[i] = (bf16_t)W2[i];
    }
}

// ---------------------------------------------------------------------------
// Pure-bf16 MFMA GEMM, global_load_lds staging, double-buffered, 32.5 KB LDS.
// MODE 1 (K=1024): epilogue relu(acc + bin[col]) -> bf16 table only.
// MODE 0 (K=256, FATTN): epilogue attention logits + bf16 xh gather table.
// Tile 128x128, BK=32, 256 threads = 4 waves (2x2), 64x64 per wave.

// stage 128x32 bf16 tile; LDS slot p of row holds global chunk p^((row>>1)&3)
__device__ __forceinline__ void stage_b(const bf16_t* __restrict__ src, int n0, int ldk,
                                        int maxrow, int k0, bf16_t* buf, int tid) {
    int w = tid >> 6, l = tid & 63;
    #pragma unroll
    for (int i = 0; i < 2; i++) {
        int gbase = w * 128 + i * 64;
        bf16_t* dst = buf + gbase * 8;     // wave-uniform base (granule*8 bf16)
        int g = gbase + l;
        int col = g >> 2, p = g & 3;
        int gs = p ^ ((col >> 1) & 3);
        int row = n0 + col;
        if (row > maxrow) row = maxrow;
        const bf16_t* gp = src + (size_t)row * ldk + k0 + gs * 8;
        GLOAD_LDS16(gp, dst);
    }
}

template<int MODE, int K, int FATTN>
__global__ __launch_bounds__(256) void gemm_mfma_kernel(
    const bf16_t* __restrict__ A16, const bf16_t* __restrict__ Bh,
    const float* __restrict__ bin, const float* __restrict__ a_src,
    const float* __restrict__ a_dst, bf16_t* __restrict__ xhb,
    float* __restrict__ al_s, float* __restrict__ al_d)
{
    __shared__ bf16_t Asb[2][128 * 32];    // 16 KB
    __shared__ bf16_t Bhs[2][128 * 32];    // 16 KB
    constexpr int NT = K / 32;

    int tid  = threadIdx.x;
    int lane = tid & 63;
    int w    = tid >> 6;
    int wr   = w >> 1, wc = w & 1;
    int r0   = blockIdx.x * 128, n0 = blockIdx.y * 128;

    f32x4 acc[4][4];
    #pragma unroll
    for (int i = 0; i < 4; i++)
        #pragma unroll
        for (int j = 0; j < 4; j++) acc[i][j] = (f32x4)0.f;

    int kc = lane >> 4, fr = lane & 15;    // kc doubles as fq in epilogue

    stage_b(A16, r0, K, NN - 1, 0, Asb[0], tid);
    stage_b(Bh, n0, K, 255, 0, Bhs[0], tid);
    __syncthreads();   // vmcnt(0) drain: tile 0 resident

    for (int t = 0; t < NT; ++t) {
        int buf = t & 1;
        if (t + 1 < NT) {   // issue next tile; lands during this compute phase
            stage_b(A16, r0, K, NN - 1, (t + 1) * 32, Asb[buf ^ 1], tid);
            stage_b(Bh, n0, K, 255, (t + 1) * 32, Bhs[buf ^ 1], tid);
        }
        // ---- fragments + MFMA ----
        const bf16_t* Ab = Asb[buf];
        const bf16_t* Hb = Bhs[buf];
        bf16x8 ahi[4];
        #pragma unroll
        for (int mf = 0; mf < 4; mf++) {
            int r  = wr * 64 + mf * 16 + fr;
            int pr = kc ^ ((r >> 1) & 3);
            ahi[mf] = *(const bf16x8*)&Ab[r * 32 + pr * 8];
        }
        #pragma unroll
        for (int nf = 0; nf < 4; nf++) {
            int c  = wc * 64 + nf * 16 + fr;
            int pr = kc ^ ((c >> 1) & 3);
            bf16x8 bhi = *(const bf16x8*)&Hb[c * 32 + pr * 8];
            #pragma unroll
            for (int mf = 0; mf < 4; mf++)
                acc[mf][nf] = mfma16(ahi[mf], bhi, acc[mf][nf]);
        }
        __syncthreads();  // tile t+1 landed; all reads of buf done
    }

    // ---- epilogue ----
    int head = blockIdx.y * 2 + wc;
    float asv[4], adv[4];
    if (FATTN) {
        #pragma unroll
        for (int nf = 0; nf < 4; nf++) {
            asv[nf] = a_src[head * 64 + nf * 16 + fr];
            adv[nf] = a_dst[head * 64 + nf * 16 + fr];
        }
    }
    #pragma unroll
    for (int mf = 0; mf < 4; mf++) {
        #pragma unroll
        for (int j = 0; j < 4; j++) {
            int row = r0 + wr * 64 + mf * 16 + kc * 4 + j;
            bool ok = row < NN;
            float s = 0.f, d = 0.f;
            #pragma unroll
            for (int nf = 0; nf < 4; nf++) {
                int col = n0 + wc * 64 + nf * 16 + fr;
                float v = acc[mf][nf][j];
                if (MODE == 1) v = fmaxf(v + bin[col], 0.f);
                if (FATTN) { s += v * asv[nf]; d += v * adv[nf]; }
                if (ok) xhb[(size_t)row * HID + col] = (bf16_t)v;   // bf16 table
            }
            if (FATTN) {
                #pragma unroll
                for (int off = 1; off < 16; off <<= 1) {
                    s += __shfl_xor(s, off);
                    d += __shfl_xor(d, off);
                }
                if (ok && fr == 0) {
                    al_s[row * 4 + head] = s;
                    al_d[row * 4 + head] = d;
                }
            }
        }
    }
}

// ---------------------------------------------------------------------------
// CSR build (by destination)
__global__ void deg_kernel(const int* __restrict__ ei, int* __restrict__ deg) {
    int e = blockIdx.x * 256 + threadIdx.x;
    if (e < EE) atomicAdd(&deg[ei[EE + e]], 1);
}

constexpr int SCB = 1024;                       // elems per scan chunk
constexpr int SCN = (NN + SCB - 1) / SCB;       // 49

// fused pass1+pass2: per-chunk sums + exclusive scan, one block of 1024
__global__ void scan12_kernel(const int* __restrict__ deg, int* __restrict__ bsum) {
    __shared__ int sh[SCN];
    int tid = threadIdx.x, w = tid >> 6, lane = tid & 63;
    for (int b = w; b < SCN; b += 16) {
        int s = 0;
        for (int i = lane; i < SCB; i += 64) {
            int idx = b * SCB + i;
            if (idx < NN) s += deg[idx];
        }
        #pragma unroll
        for (int off = 32; off; off >>= 1) s += __shfl_xor(s, off);
        if (lane == 0) sh[b] = s;
    }
    __syncthreads();
    if (tid == 0) {
        int run = 0;
        for (int b = 0; b < SCN; b++) { int v = sh[b]; bsum[b] = run; run += v; }
    }
}

__global__ void scan_pass3(const int* __restrict__ deg, const int* __restrict__ boffs,
                           int* __restrict__ row_ptr, int* __restrict__ cursor) {
    int b = blockIdx.x, t = threadIdx.x;
    int base = b * SCB + t * 4;
    int d[4]; int tot = 0;
    #pragma unroll
    for (int i = 0; i < 4; i++) { int idx = base + i; d[i] = (idx < NN) ? deg[idx] : 0; tot += d[i]; }
    int v = tot;
    for (int off = 1; off < 64; off <<= 1) {
        int u = __shfl_up(v, off);
        if ((t & 63) >= off) v += u;
    }
    __shared__ int wsum[4];
    if ((t & 63) == 63) wsum[t >> 6] = v;
    __syncthreads();
    int woff = 0;
    for (int j = 0; j < (t >> 6); j++) woff += wsum[j];
    int run = boffs[b] + woff + v - tot;
    #pragma unroll
    for (int i = 0; i < 4; i++) {
        int idx = base + i;
        if (idx < NN) {
            cursor[idx] = run;
            run += d[i];
            row_ptr[idx + 1] = run;
        }
    }
    if (b == 0 && t == 0) row_ptr[0] = 0;
}

// fill CSR with materialized src / type / weight (no eid indirection later)
__global__ void fill_kernel(const int* __restrict__ ei, const int* __restrict__ etype,
                            const float* __restrict__ ew, int* __restrict__ cursor,
                            int* __restrict__ csr_src, int* __restrict__ csr_t,
                            float* __restrict__ csr_w) {
    int e = blockIdx.x * 256 + threadIdx.x;
    if (e >= EE) return;
    int dst = ei[EE + e];
    int pos = atomicAdd(&cursor[dst], 1);
    csr_src[pos] = ei[e];
    csr_t[pos]   = etype[e];
    csr_w[pos]   = ew[e];
}

// ---------------------------------------------------------------------------
// h_new[d] = h[d] + sum_{e: dst=d} (h[src_e] + rel_emb[type_e]*w_e)
// All h reads from the bf16 table (self + gathers); accumulate fp32.
// Masked 8-deep chunks. Writes bf16 only.
__global__ void relagg_kernel(const bf16_t* __restrict__ h16, const int* __restrict__ row_ptr,
                              const int* __restrict__ csr_src, const int* __restrict__ csr_t,
                              const float* __restrict__ csr_w,
                              const float* __restrict__ rel_emb,
                              bf16_t* __restrict__ out16)
{
    int lane = threadIdx.x & 63, wid = threadIdx.x >> 6;
    int node = blockIdx.x * 4 + wid;
    if (node >= NN) return;
    int c0 = lane * 4;
    f32x4 acc = ld_bf4(h16 + (size_t)node * HID + c0);
    float wsum[5] = {0.f, 0.f, 0.f, 0.f, 0.f};
    int beg = row_ptr[node], end = row_ptr[node + 1];
    for (int k = beg; k < end; k += 8) {
        int s[8], tt[8]; float ww[8], vm[8];
        #pragma unroll
        for (int j = 0; j < 8; j++) {
            int kk = k + j;
            bool valid = kk < end;
            kk = valid ? kk : (end - 1);
            s[j]  = csr_src[kk];
            tt[j] = csr_t[kk];
            ww[j] = valid ? csr_w[kk] : 0.f;
            vm[j] = valid ? 1.f : 0.f;
        }
        f32x4 xv[8];
        #pragma unroll
        for (int j = 0; j < 8; j++) xv[j] = ld_bf4(h16 + (size_t)s[j] * HID + c0);
        #pragma unroll
        for (int j = 0; j < 8; j++) {
            acc += vm[j] * xv[j];
            #pragma unroll
            for (int r = 0; r < 5; r++) wsum[r] += (tt[j] == r) ? ww[j] : 0.f;
        }
    }
    #pragma unroll
    for (int r = 0; r < 5; r++)
        acc += wsum[r] * *(const f32x4*)(rel_emb + r * HID + c0);
    bf16x4 a16;
    #pragma unroll
    for (int i = 0; i < 4; i++) a16[i] = (bf16_t)acc[i];
    *(bf16x4*)(out16 + (size_t)node * HID + c0) = a16;
}

// GAT aggregation over bf16 xh gather table. Lane owns 4 consecutive cols
// (head lane>>4). Masked 8-deep chunks (e=-inf for invalid => exact no-op).
// Residual read from bf16 table (own node only). FINAL=0 overwrites res16
// in place (per-element read-before-write, same thread -> safe); FINAL=1
// fuses the output projection.
template<int FINAL>
__global__ void gat_kernel(const bf16_t* __restrict__ xhb, const float* __restrict__ al_s,
                           const float* __restrict__ al_d, const int* __restrict__ row_ptr,
                           const int* __restrict__ csr_src, const bf16_t* __restrict__ res16,
                           const float* __restrict__ bias, const float* __restrict__ ln_g,
                           const float* __restrict__ ln_b, bf16_t* __restrict__ out16,
                           const float* __restrict__ W_out, const float* __restrict__ b_out,
                           float* __restrict__ final_out)
{
    int lane = threadIdx.x & 63, wid = threadIdx.x >> 6;
    int node = blockIdx.x * 4 + wid;
    if (node >= NN) return;
    int hh = lane >> 4;                 // this lane's head
    int c0 = lane * 4;                  // 4 consecutive cols, all head hh

    float ald = al_d[node * 4 + hh];
    float m, den;
    f32x4 acc;

    // self-loop first (initializes the online state)
    {
        float als = al_s[node * 4 + hh];
        float e = als + ald;
        e = (e >= 0.f) ? e : 0.2f * e;
        m = e; den = 1.f;
        acc = ld_bf4(xhb + (size_t)node * HID + c0);
    }

    int beg = row_ptr[node], end = row_ptr[node + 1];
    for (int k = beg; k < end; k += 8) {
        int s[8]; float als[8];
        #pragma unroll
        for (int j = 0; j < 8; j++) {
            int kk = k + j;
            bool valid = kk < end;
            s[j] = csr_src[valid ? kk : (end - 1)];
            als[j] = valid ? 0.f : -INFINITY;   // -inf marks masked
        }
        #pragma unroll
        for (int j = 0; j < 8; j++)
            if (als[j] == 0.f) als[j] = al_s[s[j] * 4 + hh];
        f32x4 xv[8];
        #pragma unroll
        for (int j = 0; j < 8; j++) xv[j] = ld_bf4(xhb + (size_t)s[j] * HID + c0);
        #pragma unroll
        for (int j = 0; j < 8; j++) {
            float e = als[j] + ald;               // -inf stays -inf
            e = (e >= 0.f) ? e : 0.2f * e;
            float mn  = fmaxf(m, e);              // masked: mn == m
            float f   = __expf(m - mn);           // masked: 1 (exact)
            float wgt = __expf(e - mn);           // masked: 0 (exact)
            m   = mn;
            den = den * f + wgt;
            acc = acc * f + wgt * xv[j];
        }
    }

    f32x4 bia = *(const f32x4*)(bias + c0);
    f32x4 res = ld_bf4(res16 + (size_t)node * HID + c0);
    f32x4 z;
    float rd = 1.f / (den + 1e-16f);
    #pragma unroll
    for (int i = 0; i < 4; i++) z[i] = acc[i] * rd + bia[i] + res[i];

    float s = z[0] + z[1] + z[2] + z[3];
    #pragma unroll
    for (int off = 32; off; off >>= 1) s += __shfl_xor(s, off);
    float mean = s * (1.f / 256.f);
    float vp = 0.f;
    #pragma unroll
    for (int i = 0; i < 4; i++) { float d2 = z[i] - mean; vp += d2 * d2; }
    #pragma unroll
    for (int off = 32; off; off >>= 1) vp += __shfl_xor(vp, off);
    float rstd = rsqrtf(vp * (1.f / 256.f) + 1e-5f);

    f32x4 g = *(const f32x4*)(ln_g + c0);
    f32x4 bb = *(const f32x4*)(ln_b + c0);
    if (FINAL) {
        f32x4 wo = *(const f32x4*)(W_out + c0);
        float dot = 0.f;
        #pragma unroll
        for (int i = 0; i < 4; i++)
            dot += ((z[i] - mean) * rstd * g[i] + bb[i]) * wo[i];
        #pragma unroll
        for (int off = 32; off; off >>= 1) dot += __shfl_xor(dot, off);
        if (lane == 0) final_out[node] = dot + b_out[0];
    } else {
        bf16x4 o16;
        #pragma unroll
        for (int i = 0; i < 4; i++)
            o16[i] = (bf16_t)((z[i] - mean) * rstd * g[i] + bb[i]);
        *(bf16x4*)(out16 + (size_t)node * HID + c0) = o16;
    }
}

// ---------------------------------------------------------------------------
extern "C" void kernel_launch(void* const* d_in, const int* in_sizes, int n_in,
                              void* d_out, int out_size, void* d_ws, size_t ws_size,
                              hipStream_t stream) {
    const float* x       = (const float*)d_in[0];
    const int*   ei      = (const int*)d_in[1];
    const int*   etype   = (const int*)d_in[2];
    const float* ew      = (const float*)d_in[3];
    const float* rel_emb = (const float*)d_in[4];
    const float* W_in    = (const float*)d_in[5];
    const float* b_in    = (const float*)d_in[6];
    const float* W1      = (const float*)d_in[7];
    const float* a1s     = (const float*)d_in[8];
    const float* a1d     = (const float*)d_in[9];
    const float* b1      = (const float*)d_in[10];
    const float* W2      = (const float*)d_in[11];
    const float* a2s     = (const float*)d_in[12];
    const float* a2d     = (const float*)d_in[13];
    const float* b2      = (const float*)d_in[14];
    const float* ln1g    = (const float*)d_in[15];
    const float* ln1b    = (const float*)d_in[16];
    const float* ln2g    = (const float*)d_in[17];
    const float* ln2b    = (const float*)d_in[18];
    const float* W_out   = (const float*)d_in[19];
    const float* b_out   = (const float*)d_in[20];
    float* out = (float*)d_out;

    char* ws = (char*)d_ws;
    auto alloc = [&](size_t bytes) {
        void* p = (void*)ws;
        ws += (bytes + 255) & ~(size_t)255;
        return p;
    };
    bf16_t* xin16    = (bf16_t*)alloc((size_t)NN * IND * 2);   // normalized input, bf16
    bf16_t* xhb      = (bf16_t*)alloc((size_t)NN * HID * 2);   // xh gather table
    bf16_t* gin16    = (bf16_t*)alloc((size_t)NN * HID * 2);   // h / residual table
    bf16_t* hb16     = (bf16_t*)alloc((size_t)NN * HID * 2);   // bf16 h0
    bf16_t* wmh      = (bf16_t*)alloc((size_t)HID * IND * 2);
    bf16_t* w1h      = (bf16_t*)alloc((size_t)HID * HID * 2);
    bf16_t* w2h      = (bf16_t*)alloc((size_t)HID * HID * 2);
    float*  stats_s  = (float*)alloc(512 * 4);
    float*  al_s     = (float*)alloc((size_t)NN * 4 * 4);
    float*  al_d     = (float*)alloc((size_t)NN * 4 * 4);
    int*    deg      = (int*)alloc((size_t)NN * 4);
    int*    row_ptr  = (int*)alloc((size_t)(NN + 1) * 4);
    int*    cursor   = (int*)alloc((size_t)NN * 4);
    int*    csr_src  = (int*)alloc((size_t)EE * 4);
    int*    csr_t    = (int*)alloc((size_t)EE * 4);
    float*  csr_w    = (float*)alloc((size_t)EE * 4);
    int*    bsum     = (int*)alloc(64 * 4);

    hipMemsetAsync(stats_s, 0, 512 * 4, stream);
    hipMemsetAsync(deg, 0, (size_t)NN * 4, stream);

    // input feature prep
    colstats_kernel<<<1024, 256, 0, stream>>>(x, stats_s);
    xin_kernel<<<(NN + 3) / 4, 256, 0, stream>>>(x, stats_s, xin16);
    prep_all_kernel<<<1536, 256, 0, stream>>>(W_in, W1, W2, wmh, w1h, w2h);

    // CSR build
    deg_kernel<<<(EE + 255) / 256, 256, 0, stream>>>(ei, deg);
    scan12_kernel<<<1, 1024, 0, stream>>>(deg, bsum);
    scan_pass3<<<SCN, 256, 0, stream>>>(deg, bsum, row_ptr, cursor);
    fill_kernel<<<(EE + 255) / 256, 256, 0, stream>>>(ei, etype, ew, cursor,
                                                      csr_src, csr_t, csr_w);

    dim3 g1(NRT, 2);

    // h0 = relu(xin @ W_in^T + b_in)  -> hb16 (bf16)
    gemm_mfma_kernel<1, 1024, 0><<<g1, 256, 0, stream>>>(
        xin16, wmh, b_in, nullptr, nullptr, hb16, nullptr, nullptr);

    int nodeBlocks = (NN + 3) / 4;

    // relational aggregation (bf16 reads) -> gin16 (bf16 h / residual table)
    relagg_kernel<<<nodeBlocks, 256, 0, stream>>>(hb16, row_ptr, csr_src, csr_t,
                                                  csr_w, rel_emb, gin16);

    // ---- GAT layer 1 (bf16 xh GEMM -> xhb + fused attention logits) ----
    gemm_mfma_kernel<0, 256, 1><<<g1, 256, 0, stream>>>(
        gin16, w1h, nullptr, a1s, a1d, xhb, al_s, al_d);
    // gat<0>: residual from gin16, overwrites gin16 in place (h1 table)
    gat_kernel<0><<<nodeBlocks, 256, 0, stream>>>(xhb, al_s, al_d, row_ptr, csr_src,
                                                  gin16, b1, ln1g, ln1b, gin16,
                                                  nullptr, nullptr, nullptr);

    // ---- GAT layer 2 (final projection fused) ----
    gemm_mfma_kernel<0, 256, 1><<<g1, 256, 0, stream>>>(
        gin16, w2h, nullptr, a2s, a2d, xhb, al_s, al_d);
    gat_kernel<1><<<nodeBlocks, 256, 0, stream>>>(xhb, al_s, al_d, row_ptr, csr_src,
                                                  gin16, b2, ln2g, ln2b, nullptr,
                                                  W_out, b_out, out);
}